// Round 1
// baseline (208.659 us; speedup 1.0000x reference)
//
#include <hip/hip_runtime.h>

typedef _Float16 h16;
typedef __attribute__((ext_vector_type(2))) _Float16 f16x2;
typedef __attribute__((ext_vector_type(4))) _Float16 f16x4;
typedef __attribute__((ext_vector_type(2))) __fp16   fp16x2n;   // native return of cvt_pkrtz
typedef __attribute__((ext_vector_type(8))) _Float16 f16x8;
typedef __attribute__((ext_vector_type(4))) float f32x4;

#define S_LEN 4096
#define NHEAD 16
#define HDIM  64
#define WIN   128
#define TQ    256
#define NQT   (S_LEN / TQ)   // 16 q-tiles
#define NCHT  16             // chunks of 32 keys covering rel window [0, 512)
#define KSTR  72             // f16 per K row   (144 B, 16B-aligned)
#define VSTR2 40             // f16 per V^T row (80 B, 16B-aligned)
#define SSTR  40             // f16 per P row
#define QSCALE 0.18033688011112042f   // h^-0.5 * log2(e); scores in log2 domain

static __device__ __forceinline__ f16x2 pk(float a, float b) {
    fp16x2n r = __builtin_amdgcn_cvt_pkrtz(a, b);
    return __builtin_bit_cast(f16x2, r);
}

static __device__ __forceinline__ f16x8 cvt8(float4 a, float4 b) {
    f16x2 p0 = pk(a.x, a.y), p1 = pk(a.z, a.w);
    f16x2 p2 = pk(b.x, b.y), p3 = pk(b.z, b.w);
    f16x8 r;
    r[0]=p0[0]; r[1]=p0[1]; r[2]=p1[0]; r[3]=p1[1];
    r[4]=p2[0]; r[5]=p2[1]; r[6]=p3[0]; r[7]=p3[1];
    return r;
}

// TQ=256 via 1024 threads (16 waves x 16 query rows): K/V halo re-read drops
// 3x -> 2x (fetch 235 -> 168 MB). 2 blocks/CU x 16 waves = 32 waves/CU (max),
// needs VGPR <= 64 -> __launch_bounds__(1024, 8). LDS 49664 B < 64 KB static.
// Grid 16x16x2 = 512 = 256 CUs x 2 -> exactly one residency wave.
__global__ __launch_bounds__(1024, 8)
void wattn(const float* __restrict__ Qg, const float* __restrict__ Kg,
           const float* __restrict__ Vg, float* __restrict__ Og)
{
    __shared__ h16 Kbuf[3][32 * KSTR];    // 3 x 4608 B, [key][h]
    __shared__ h16 Vbuf[3][64 * VSTR2];   // 3 x 5120 B, V^T [h][key'] (swizzled key)
    __shared__ h16 Slds[16 * 16 * SSTR];  // per-wave P tile (swizzled col), 20480 B

    const int tid  = threadIdx.x;
    const int wid  = tid >> 6;
    const int lane = tid & 63;
    const int l15  = lane & 15;
    const int quad = lane >> 4;

    // XCD-chunked swizzle: HW round-robins linear block id across 8 XCDs; remap
    // so XCD k gets a contiguous chunk = 4 whole (head,b) panels (K+V = 2 MB
    // each, L2-fit) instead of scattering all 32 panels across every XCD.
    int lin = blockIdx.x + NQT * (blockIdx.y + NHEAD * blockIdx.z);
    int nwg = NQT * NHEAD * gridDim.z;
    int swz = ((nwg & 7) == 0) ? ((lin & 7) * (nwg >> 3) + (lin >> 3)) : lin;
    const int bx   = swz & (NQT - 1);
    const int head = (swz / NQT) & (NHEAD - 1);
    const int b    = swz / (NQT * NHEAD);

    const int q0    = bx * TQ;
    const int kbase = q0 - WIN;
    const int rowstride = NHEAD * HDIM;   // 1024 floats between seq positions

    const float* KB = Kg + ((long)b * S_LEN * NHEAD + head) * HDIM;
    const float* VB = Vg + ((long)b * S_LEN * NHEAD + head) * HDIM;

    // staging: 16 lanes cover one key row's 256 B contiguously; waves 0-7 stage
    // K, waves 8-15 stage V (wave-uniform split, one float4 per thread).
    const bool isK = (tid < 512);
    const int srow = (tid >> 4) & 31;     // 0..31 key-in-chunk
    const int ish  = tid & 15;            // h-quad index
    const int sh0  = ish * 4;             // h offset (x4 floats = 16 B)
    // V^T key swizzle: rotate key block by h-bits 4-5, XOR bits 3-4 with h-bits
    // 2-3. Breaks the 16-way fold (h-stride 40 h16 = 20 dw ≡ {0,16} mod 32
    // across the 16 sh0 lanes) down to ~4-way. Read side inverts it per (t,l15)
    // while staying f16x8-contiguous (only key bits >=3 touched).
    const int vkey = ((srow + (((ish >> 2) & 3) << 3)) & 31) ^ ((ish & 3) << 3);
    const float* SB = isK ? KB : VB;

    float4 sreg;
    #define SLOAD(i) do {                                                    \
        int kg_ = kbase + (i)*32 + srow;                                     \
        kg_ = kg_ < 0 ? 0 : (kg_ > S_LEN-1 ? S_LEN-1 : kg_);                 \
        sreg = *(const float4*)(SB + (long)kg_ * rowstride + sh0);           \
    } while (0)
    #define SWRITE(i) do {                                                   \
        int bi_ = (i) % 3;                                                   \
        if (isK) {                                                           \
            f16x2 ka_ = pk(sreg.x, sreg.y), kb_ = pk(sreg.z, sreg.w);        \
            f16x4 kv_; kv_[0]=ka_[0]; kv_[1]=ka_[1]; kv_[2]=kb_[0]; kv_[3]=kb_[1];\
            *(f16x4*)&Kbuf[bi_][srow * KSTR + sh0] = kv_;                    \
        } else {                                                             \
            Vbuf[bi_][(sh0+0) * VSTR2 + vkey] = (h16)sreg.x;                 \
            Vbuf[bi_][(sh0+1) * VSTR2 + vkey] = (h16)sreg.y;                 \
            Vbuf[bi_][(sh0+2) * VSTR2 + vkey] = (h16)sreg.z;                 \
            Vbuf[bi_][(sh0+3) * VSTR2 + vkey] = (h16)sreg.w;                 \
        }                                                                    \
    } while (0)

    SLOAD(0);

    // ---- Q fragments (pre-scaled by h^-0.5 * log2e), A-layout ----
    f16x8 aQ0, aQ1;
    {
        const int qrow = q0 + wid * 16 + l15;
        const float* qp = Qg + ((long)(b * S_LEN + qrow) * NHEAD + head) * HDIM;
        float4 x0 = *(const float4*)(qp + quad*8);
        float4 x1 = *(const float4*)(qp + quad*8 + 4);
        float4 x2 = *(const float4*)(qp + 32 + quad*8);
        float4 x3 = *(const float4*)(qp + 32 + quad*8 + 4);
        x0.x*=QSCALE; x0.y*=QSCALE; x0.z*=QSCALE; x0.w*=QSCALE;
        x1.x*=QSCALE; x1.y*=QSCALE; x1.z*=QSCALE; x1.w*=QSCALE;
        x2.x*=QSCALE; x2.y*=QSCALE; x2.z*=QSCALE; x2.w*=QSCALE;
        x3.x*=QSCALE; x3.y*=QSCALE; x3.z*=QSCALE; x3.w*=QSCALE;
        aQ0 = cvt8(x0, x1);
        aQ1 = cvt8(x2, x3);
    }

    SWRITE(0);
    __syncthreads();

    // per-row window bounds
    int lo[4], hi[4];
    #pragma unroll
    for (int r = 0; r < 4; ++r) {
        int qg = q0 + wid*16 + quad*4 + r;
        lo[r] = (qg - WIN < 0) ? 0 : qg - WIN;
        hi[r] = (qg + WIN > S_LEN-1) ? S_LEN-1 : qg + WIN;
    }

    float l_r[4] = {0.f, 0.f, 0.f, 0.f};
    f32x4 Oacc[4];
    #pragma unroll
    for (int t = 0; t < 4; ++t) Oacc[t] = (f32x4){0.f,0.f,0.f,0.f};

    const int c0 = wid >> 1;   // wave's 9 relevant chunks: [c0, c0+9)
    h16* Sw = &Slds[wid * 16 * SSTR];
    const int pxw = quad << 3;             // P write-side col XOR (row>>2 = quad)
    const int pxr = (l15 & 12) << 1;       // P/V read-side col XOR (row = l15)

    for (int i = 0; i < NCHT; ++i) {
        if (i + 1 < NCHT) SLOAD(i + 1);   // in flight across compute

        if ((unsigned)(i - c0) < 9u) {
            const h16* Kb = Kbuf[i % 3];
            const h16* Vb = Vbuf[i % 3];

            f16x8 bK00 = *(const f16x8*)&Kb[ l15      * KSTR + quad*8];
            f16x8 bK01 = *(const f16x8*)&Kb[ l15      * KSTR + 32 + quad*8];
            f16x8 bK10 = *(const f16x8*)&Kb[(16+l15)  * KSTR + quad*8];
            f16x8 bK11 = *(const f16x8*)&Kb[(16+l15)  * KSTR + 32 + quad*8];

            f32x4 s0 = (f32x4){0.f,0.f,0.f,0.f};
            s0 = __builtin_amdgcn_mfma_f32_16x16x32_f16(aQ0, bK00, s0, 0, 0, 0);
            s0 = __builtin_amdgcn_mfma_f32_16x16x32_f16(aQ1, bK01, s0, 0, 0, 0);
            f32x4 s1 = (f32x4){0.f,0.f,0.f,0.f};
            s1 = __builtin_amdgcn_mfma_f32_16x16x32_f16(aQ0, bK10, s1, 0, 0, 0);
            s1 = __builtin_amdgcn_mfma_f32_16x16x32_f16(aQ1, bK11, s1, 0, 0, 0);

            const int col0 = kbase + i*32 + l15;
            const int col1 = col0 + 16;
            #pragma unroll
            for (int r = 0; r < 4; ++r) {
                float v0 = (col0 >= lo[r] && col0 <= hi[r]) ? s0[r] : -1e30f;
                float v1 = (col1 >= lo[r] && col1 <= hi[r]) ? s1[r] : -1e30f;
                float p0 = exp2f(v0);     // exp2(-1e30)=0 -> clamped K/V rows vanish
                float p1 = exp2f(v1);
                l_r[r] += p0 + p1;
                // col XOR'd with (row>>2): spreads the 4 quads over all banks
                Sw[(quad*4 + r) * SSTR + ( l15       ^ pxw)] = (h16)p0;
                Sw[(quad*4 + r) * SSTR + ((16 + l15) ^ pxw)] = (h16)p1;
            }

            __builtin_amdgcn_wave_barrier();   // wave-private P round-trip

            f16x8 aP = *(const f16x8*)&Sw[l15 * SSTR + ((quad*8) ^ pxr)];
            #pragma unroll
            for (int t = 0; t < 4; ++t) {
                // invert the V key swizzle: rot by t (h bits 4-5), XOR by l15>>2
                f16x8 bV = *(const f16x8*)&Vb[(t*16 + l15) * VSTR2 +
                                              (((quad*8 + (t << 3)) & 31) ^ pxr)];
                Oacc[t] = __builtin_amdgcn_mfma_f32_16x16x32_f16(aP, bV, Oacc[t], 0, 0, 0);
            }
            __builtin_amdgcn_wave_barrier();
        }

        if (i + 1 < NCHT) SWRITE(i + 1);  // to buf (i+1)%3: nobody reads it this iter
        __syncthreads();                   // one barrier per chunk (triple buffer)
    }
    #undef SLOAD
    #undef SWRITE

    // ---- epilogue: l-reduction across the 16-lane row group, store ----
    float* op = Og + ((long)(b * S_LEN + q0 + wid*16) * NHEAD + head) * HDIM;
    #pragma unroll
    for (int r = 0; r < 4; ++r) {
        float l = l_r[r];
        l += __shfl_xor(l, 1);
        l += __shfl_xor(l, 2);
        l += __shfl_xor(l, 4);
        l += __shfl_xor(l, 8);
        float inv = 1.0f / l;
        #pragma unroll
        for (int t = 0; t < 4; ++t) {
            op[(quad*4 + r) * rowstride + t*16 + l15] = Oacc[t][r] * inv;
        }
    }
}

extern "C" void kernel_launch(void* const* d_in, const int* in_sizes, int n_in,
                              void* d_out, int out_size, void* d_ws, size_t ws_size,
                              hipStream_t stream) {
    const float* q = (const float*)d_in[0];
    const float* k = (const float*)d_in[1];
    const float* v = (const float*)d_in[2];
    float* out = (float*)d_out;
    const int batch = in_sizes[0] / (S_LEN * NHEAD * HDIM);
    dim3 grid(NQT, NHEAD, batch);
    wattn<<<grid, 1024, 0, stream>>>(q, k, v, out);
}

// Round 2
// 149.618 us; speedup vs baseline: 1.3946x; 1.3946x over previous
//
#include <hip/hip_runtime.h>

typedef _Float16 h16;
typedef __attribute__((ext_vector_type(2))) _Float16 f16x2;
typedef __attribute__((ext_vector_type(4))) _Float16 f16x4;
typedef __attribute__((ext_vector_type(2))) __fp16   fp16x2n;   // native return of cvt_pkrtz
typedef __attribute__((ext_vector_type(8))) _Float16 f16x8;
typedef __attribute__((ext_vector_type(4))) float f32x4;

#define S_LEN 4096
#define NHEAD 16
#define HDIM  64
#define WIN   128
#define TQ    128
#define NQT   (S_LEN / TQ)   // 32 q-tiles
#define NCHT  12    // chunks of 32 keys covering rel window [0, 384)
#define KSTR  72    // f16 per K row   (144 B, 16B-aligned)
#define VSTR2 40    // f16 per V^T row (80 B, 16B-aligned)
#define SSTR  40    // f16 per P row
#define QSCALE 0.18033688011112042f   // h^-0.5 * log2(e); scores in log2 domain

static __device__ __forceinline__ f16x2 pk(float a, float b) {
    fp16x2n r = __builtin_amdgcn_cvt_pkrtz(a, b);
    return __builtin_bit_cast(f16x2, r);
}

static __device__ __forceinline__ f16x8 cvt8(float4 a, float4 b) {
    f16x2 p0 = pk(a.x, a.y), p1 = pk(a.z, a.w);
    f16x2 p2 = pk(b.x, b.y), p3 = pk(b.z, b.w);
    f16x8 r;
    r[0]=p0[0]; r[1]=p0[1]; r[2]=p1[0]; r[3]=p1[1];
    r[4]=p2[0]; r[5]=p2[1]; r[6]=p3[0]; r[7]=p3[1];
    return r;
}

// (512,4): 64-VGPR budget -> 4 blocks/CU, body ~50 VGPRs, no spill (the R1
// (1024,8) config spilled to scratch: WRITE_SIZE 33->142 MB, dur 66->111 us).
// LDS 4 x 39424 B = 157.7 KB <= 160 KB; 2048 threads = CU max. Grid 1024 =
// 256 CUs x 4 -> exactly ONE residency wave.
__global__ __launch_bounds__(512, 4)
void wattn(const float* __restrict__ Qg, const float* __restrict__ Kg,
           const float* __restrict__ Vg, float* __restrict__ Og)
{
    __shared__ h16 Kbuf[3][32 * KSTR];    // 3 x 4608 B, [key][h]
    __shared__ h16 Vbuf[3][64 * VSTR2];   // 3 x 5120 B, V^T [h][key'] (swizzled key)
    __shared__ h16 Slds[8 * 16 * SSTR];   // per-wave P tile (swizzled col), 10240 B

    const int tid  = threadIdx.x;
    const int wid  = tid >> 6;
    const int lane = tid & 63;
    const int l15  = lane & 15;
    const int quad = lane >> 4;

    // XCD-chunked bijective swizzle: linear id round-robins over 8 XCDs; remap
    // so each XCD owns 128 consecutive blocks = 4 whole (head,b) K/V panels.
    // The 3 blocks sharing a halo key then run concurrently on ONE XCD's L2.
    int lin = blockIdx.x + NQT * (blockIdx.y + NHEAD * blockIdx.z);
    int nwg = NQT * NHEAD * gridDim.z;
    int swz = ((nwg & 7) == 0) ? ((lin & 7) * (nwg >> 3) + (lin >> 3)) : lin;
    const int bx   = swz & (NQT - 1);
    const int head = (swz / NQT) & (NHEAD - 1);
    const int b    = swz / (NQT * NHEAD);

    const int q0    = bx * TQ;
    const int kbase = q0 - WIN;
    const int rowstride = NHEAD * HDIM;   // 1024 floats between seq positions

    const float* KB = Kg + ((long)b * S_LEN * NHEAD + head) * HDIM;
    const float* VB = Vg + ((long)b * S_LEN * NHEAD + head) * HDIM;

    // staging assignment: 16 lanes cover one key row's 256 B contiguously
    const int srow = tid >> 4;            // 0..31 key-in-chunk
    const int ish  = tid & 15;            // h-quad index
    const int sh0  = ish * 4;             // h offset (x4 floats = 16 B)
    // V^T key swizzle (refchecked in R1): rotate key block by h-bits 4-5, XOR
    // key bits 3-4 with h-bits 2-3. Unswizzled V-write is a 16-way bank
    // conflict (h-stride 40 h16 = 20 dw folds 16 sh0 lanes onto banks {0,16});
    // swizzled write is 2-way (free). Read side inverts per (t,l15), staying
    // f16x8-contiguous (only key bits >=3 touched).
    const int vkey = ((srow + (((ish >> 2) & 3) << 3)) & 31) ^ ((ish & 3) << 3);

    float4 kreg, vreg;
    #define SLOAD(i) do {                                                    \
        int kg_ = kbase + (i)*32 + srow;                                     \
        kg_ = kg_ < 0 ? 0 : (kg_ > S_LEN-1 ? S_LEN-1 : kg_);                 \
        const float* kp_ = KB + (long)kg_ * rowstride + sh0;                 \
        const float* vp_ = VB + (long)kg_ * rowstride + sh0;                 \
        kreg = *(const float4*)kp_;                                          \
        vreg = *(const float4*)vp_;                                          \
    } while (0)
    #define SWRITE(i) do {                                                   \
        int bi_ = (i) % 3;                                                   \
        f16x2 ka_ = pk(kreg.x, kreg.y), kb_ = pk(kreg.z, kreg.w);            \
        f16x4 kv_; kv_[0]=ka_[0]; kv_[1]=ka_[1]; kv_[2]=kb_[0]; kv_[3]=kb_[1];\
        *(f16x4*)&Kbuf[bi_][srow * KSTR + sh0] = kv_;                        \
        Vbuf[bi_][(sh0+0) * VSTR2 + vkey] = (h16)vreg.x;                     \
        Vbuf[bi_][(sh0+1) * VSTR2 + vkey] = (h16)vreg.y;                     \
        Vbuf[bi_][(sh0+2) * VSTR2 + vkey] = (h16)vreg.z;                     \
        Vbuf[bi_][(sh0+3) * VSTR2 + vkey] = (h16)vreg.w;                     \
    } while (0)

    SLOAD(0);

    // ---- Q fragments (pre-scaled by h^-0.5 * log2e), A-layout ----
    f16x8 aQ0, aQ1;
    {
        const int qrow = q0 + wid * 16 + l15;
        const float* qp = Qg + ((long)(b * S_LEN + qrow) * NHEAD + head) * HDIM;
        float4 x0 = *(const float4*)(qp + quad*8);
        float4 x1 = *(const float4*)(qp + quad*8 + 4);
        float4 x2 = *(const float4*)(qp + 32 + quad*8);
        float4 x3 = *(const float4*)(qp + 32 + quad*8 + 4);
        x0.x*=QSCALE; x0.y*=QSCALE; x0.z*=QSCALE; x0.w*=QSCALE;
        x1.x*=QSCALE; x1.y*=QSCALE; x1.z*=QSCALE; x1.w*=QSCALE;
        x2.x*=QSCALE; x2.y*=QSCALE; x2.z*=QSCALE; x2.w*=QSCALE;
        x3.x*=QSCALE; x3.y*=QSCALE; x3.z*=QSCALE; x3.w*=QSCALE;
        aQ0 = cvt8(x0, x1);
        aQ1 = cvt8(x2, x3);
    }

    SWRITE(0);
    __syncthreads();

    // per-row window bounds
    int lo[4], hi[4];
    #pragma unroll
    for (int r = 0; r < 4; ++r) {
        int qg = q0 + wid*16 + quad*4 + r;
        lo[r] = (qg - WIN < 0) ? 0 : qg - WIN;
        hi[r] = (qg + WIN > S_LEN-1) ? S_LEN-1 : qg + WIN;
    }

    float l_r[4] = {0.f, 0.f, 0.f, 0.f};
    f32x4 Oacc[4];
    #pragma unroll
    for (int t = 0; t < 4; ++t) Oacc[t] = (f32x4){0.f,0.f,0.f,0.f};

    const int c0 = wid >> 1;   // wave's 9 relevant chunks: [c0, c0+9)
    h16* Sw = &Slds[wid * 16 * SSTR];
    const int pxw = quad << 3;             // P write-side col XOR (row>>2 = quad)
    const int pxr = (l15 & 12) << 1;       // P/V read-side col XOR (row = l15)

    for (int i = 0; i < NCHT; ++i) {
        if (i + 1 < NCHT) SLOAD(i + 1);   // in flight across compute

        if ((unsigned)(i - c0) < 9u) {
            const h16* Kb = Kbuf[i % 3];
            const h16* Vb = Vbuf[i % 3];

            f16x8 bK00 = *(const f16x8*)&Kb[ l15      * KSTR + quad*8];
            f16x8 bK01 = *(const f16x8*)&Kb[ l15      * KSTR + 32 + quad*8];
            f16x8 bK10 = *(const f16x8*)&Kb[(16+l15)  * KSTR + quad*8];
            f16x8 bK11 = *(const f16x8*)&Kb[(16+l15)  * KSTR + 32 + quad*8];

            f32x4 s0 = (f32x4){0.f,0.f,0.f,0.f};
            s0 = __builtin_amdgcn_mfma_f32_16x16x32_f16(aQ0, bK00, s0, 0, 0, 0);
            s0 = __builtin_amdgcn_mfma_f32_16x16x32_f16(aQ1, bK01, s0, 0, 0, 0);
            f32x4 s1 = (f32x4){0.f,0.f,0.f,0.f};
            s1 = __builtin_amdgcn_mfma_f32_16x16x32_f16(aQ0, bK10, s1, 0, 0, 0);
            s1 = __builtin_amdgcn_mfma_f32_16x16x32_f16(aQ1, bK11, s1, 0, 0, 0);

            const int col0 = kbase + i*32 + l15;
            const int col1 = col0 + 16;
            #pragma unroll
            for (int r = 0; r < 4; ++r) {
                float v0 = (col0 >= lo[r] && col0 <= hi[r]) ? s0[r] : -1e30f;
                float v1 = (col1 >= lo[r] && col1 <= hi[r]) ? s1[r] : -1e30f;
                float p0 = exp2f(v0);     // exp2(-1e30)=0 -> clamped K/V rows vanish
                float p1 = exp2f(v1);
                l_r[r] += p0 + p1;
                // col XOR'd with 8*(row>>2): write lands 2-way (free)
                Sw[(quad*4 + r) * SSTR + ( l15       ^ pxw)] = (h16)p0;
                Sw[(quad*4 + r) * SSTR + ((16 + l15) ^ pxw)] = (h16)p1;
            }

            __builtin_amdgcn_wave_barrier();   // wave-private P round-trip

            f16x8 aP = *(const f16x8*)&Sw[l15 * SSTR + ((quad*8) ^ pxr)];
            #pragma unroll
            for (int t = 0; t < 4; ++t) {
                // invert the V key swizzle: rot by t (h bits 4-5), XOR by l15>>2
                f16x8 bV = *(const f16x8*)&Vb[(t*16 + l15) * VSTR2 +
                                              (((quad*8 + (t << 3)) & 31) ^ pxr)];
                Oacc[t] = __builtin_amdgcn_mfma_f32_16x16x32_f16(aP, bV, Oacc[t], 0, 0, 0);
            }
            __builtin_amdgcn_wave_barrier();
        }

        if (i + 1 < NCHT) SWRITE(i + 1);  // to buf (i+1)%3: nobody reads it this iter
        __syncthreads();                   // one barrier per chunk (triple buffer)
    }
    #undef SLOAD
    #undef SWRITE

    // ---- epilogue: l-reduction across the 16-lane row group, store ----
    float* op = Og + ((long)(b * S_LEN + q0 + wid*16) * NHEAD + head) * HDIM;
    #pragma unroll
    for (int r = 0; r < 4; ++r) {
        float l = l_r[r];
        l += __shfl_xor(l, 1);
        l += __shfl_xor(l, 2);
        l += __shfl_xor(l, 4);
        l += __shfl_xor(l, 8);
        float inv = 1.0f / l;
        #pragma unroll
        for (int t = 0; t < 4; ++t) {
            op[(quad*4 + r) * rowstride + t*16 + l15] = Oacc[t][r] * inv;
        }
    }
}

extern "C" void kernel_launch(void* const* d_in, const int* in_sizes, int n_in,
                              void* d_out, int out_size, void* d_ws, size_t ws_size,
                              hipStream_t stream) {
    const float* q = (const float*)d_in[0];
    const float* k = (const float*)d_in[1];
    const float* v = (const float*)d_in[2];
    float* out = (float*)d_out;
    const int batch = in_sizes[0] / (S_LEN * NHEAD * HDIM);
    dim3 grid(NQT, NHEAD, batch);
    wattn<<<grid, 512, 0, stream>>>(q, k, v, out);
}

// Round 3
// 148.323 us; speedup vs baseline: 1.4068x; 1.0087x over previous
//
#include <hip/hip_runtime.h>

typedef _Float16 h16;
typedef __attribute__((ext_vector_type(2))) _Float16 f16x2;
typedef __attribute__((ext_vector_type(4))) _Float16 f16x4;
typedef __attribute__((ext_vector_type(2))) __fp16   fp16x2n;   // native return of cvt_pkrtz
typedef __attribute__((ext_vector_type(8))) _Float16 f16x8;
typedef __attribute__((ext_vector_type(4))) float f32x4;
typedef __attribute__((ext_vector_type(4))) int   i32x4;

#define S_LEN 4096
#define NHEAD 16
#define HDIM  64
#define WIN   128
#define TQ    128
#define NQT   (S_LEN / TQ)   // 32 q-tiles
#define NCHT  12    // chunks of 32 keys covering rel window [0, 384)
#define KSTR  72    // f16 per K row   (144 B, 16B-aligned)
#define VSTR2 40    // f16 per V^T row (80 B, 16B-aligned)
#define QSCALE 0.18033688011112042f   // h^-0.5 * log2(e); scores in log2 domain

static __device__ __forceinline__ f16x2 pk(float a, float b) {
    fp16x2n r = __builtin_amdgcn_cvt_pkrtz(a, b);
    return __builtin_bit_cast(f16x2, r);
}

static __device__ __forceinline__ f16x8 cvt8(float4 a, float4 b) {
    f16x2 p0 = pk(a.x, a.y), p1 = pk(a.z, a.w);
    f16x2 p2 = pk(b.x, b.y), p3 = pk(b.z, b.w);
    f16x8 r;
    r[0]=p0[0]; r[1]=p0[1]; r[2]=p1[0]; r[3]=p1[1];
    r[4]=p2[0]; r[5]=p2[1]; r[6]=p3[0]; r[7]=p3[1];
    return r;
}

// (512,4): 64-VGPR budget -> 4 blocks/CU, no spill (R1's (1024,8) spilled:
// WRITE 33->142 MB). LDS now 4 x 29184 B = 116.7 KB (P tile eliminated —
// in-register transpose). Grid 1024 = 256 CUs x 4 -> one residency wave.
__global__ __launch_bounds__(512, 4)
void wattn(const float* __restrict__ Qg, const float* __restrict__ Kg,
           const float* __restrict__ Vg, float* __restrict__ Og)
{
    __shared__ h16 Kbuf[3][32 * KSTR];    // 3 x 4608 B, [key][h]
    __shared__ h16 Vbuf[3][64 * VSTR2];   // 3 x 5120 B, V^T [h][key'] (swizzled key)

    const int tid  = threadIdx.x;
    const int wid  = tid >> 6;
    const int lane = tid & 63;
    const int l15  = lane & 15;
    const int quad = lane >> 4;

    // XCD-chunked bijective swizzle: each XCD owns 128 consecutive blocks =
    // 4 whole (head,b) K/V panels -> halo re-reads hit that XCD's L2.
    // (R2 measured FETCH 66 MB ~= 1x compulsory traffic: it works.)
    int lin = blockIdx.x + NQT * (blockIdx.y + NHEAD * blockIdx.z);
    int nwg = NQT * NHEAD * gridDim.z;
    int swz = ((nwg & 7) == 0) ? ((lin & 7) * (nwg >> 3) + (lin >> 3)) : lin;
    const int bx   = swz & (NQT - 1);
    const int head = (swz / NQT) & (NHEAD - 1);
    const int b    = swz / (NQT * NHEAD);

    const int q0    = bx * TQ;
    const int kbase = q0 - WIN;
    const int rowstride = NHEAD * HDIM;   // 1024 floats between seq positions

    const float* KB = Kg + ((long)b * S_LEN * NHEAD + head) * HDIM;
    const float* VB = Vg + ((long)b * S_LEN * NHEAD + head) * HDIM;

    // staging assignment: 16 lanes cover one key row's 256 B contiguously
    const int srow = tid >> 4;            // 0..31 key-in-chunk
    const int ish  = tid & 15;            // h-quad index
    const int sh0  = ish * 4;             // h offset (x4 floats = 16 B)
    // V^T key swizzle (refchecked R1/R2): breaks the 16-way write fold.
    const int vkey = ((srow + (((ish >> 2) & 3) << 3)) & 31) ^ ((ish & 3) << 3);

    float4 kreg, vreg;
    #define SLOAD(i) do {                                                    \
        int kg_ = kbase + (i)*32 + srow;                                     \
        kg_ = kg_ < 0 ? 0 : (kg_ > S_LEN-1 ? S_LEN-1 : kg_);                 \
        const float* kp_ = KB + (long)kg_ * rowstride + sh0;                 \
        const float* vp_ = VB + (long)kg_ * rowstride + sh0;                 \
        kreg = *(const float4*)kp_;                                          \
        vreg = *(const float4*)vp_;                                          \
    } while (0)
    #define SWRITE(i) do {                                                   \
        int bi_ = (i) % 3;                                                   \
        f16x2 ka_ = pk(kreg.x, kreg.y), kb_ = pk(kreg.z, kreg.w);            \
        f16x4 kv_; kv_[0]=ka_[0]; kv_[1]=ka_[1]; kv_[2]=kb_[0]; kv_[3]=kb_[1];\
        *(f16x4*)&Kbuf[bi_][srow * KSTR + sh0] = kv_;                        \
        Vbuf[bi_][(sh0+0) * VSTR2 + vkey] = (h16)vreg.x;                     \
        Vbuf[bi_][(sh0+1) * VSTR2 + vkey] = (h16)vreg.y;                     \
        Vbuf[bi_][(sh0+2) * VSTR2 + vkey] = (h16)vreg.z;                     \
        Vbuf[bi_][(sh0+3) * VSTR2 + vkey] = (h16)vreg.w;                     \
    } while (0)

    SLOAD(0);

    // ---- Q fragments (pre-scaled by h^-0.5 * log2e) ----
    // Used as the B-operand of the SWAPPED QK^T: mfma(K, Q) -> S^T, so each
    // lane l15 owns one q-row of P (row-reduce and PV A-operand become
    // lane-local; no P LDS round-trip).
    f16x8 aQ0, aQ1;
    {
        const int qrow = q0 + wid * 16 + l15;
        const float* qp = Qg + ((long)(b * S_LEN + qrow) * NHEAD + head) * HDIM;
        float4 x0 = *(const float4*)(qp + quad*8);
        float4 x1 = *(const float4*)(qp + quad*8 + 4);
        float4 x2 = *(const float4*)(qp + 32 + quad*8);
        float4 x3 = *(const float4*)(qp + 32 + quad*8 + 4);
        x0.x*=QSCALE; x0.y*=QSCALE; x0.z*=QSCALE; x0.w*=QSCALE;
        x1.x*=QSCALE; x1.y*=QSCALE; x1.z*=QSCALE; x1.w*=QSCALE;
        x2.x*=QSCALE; x2.y*=QSCALE; x2.z*=QSCALE; x2.w*=QSCALE;
        x3.x*=QSCALE; x3.y*=QSCALE; x3.z*=QSCALE; x3.w*=QSCALE;
        aQ0 = cvt8(x0, x1);
        aQ1 = cvt8(x2, x3);
    }

    SWRITE(0);
    SLOAD(1);          // in flight across the barrier; consumed at iter 0 start
    __syncthreads();

    // per-lane window bounds (lane's q-row is l15)
    const int qg = q0 + wid*16 + l15;
    const int lo = (qg - WIN < 0) ? 0 : qg - WIN;
    const int hi = (qg + WIN > S_LEN-1) ? S_LEN-1 : qg + WIN;
    const unsigned span = (unsigned)(hi - lo);

    float l_lane = 0.f;
    f32x4 Oacc[4];
    #pragma unroll
    for (int t = 0; t < 4; ++t) Oacc[t] = (f32x4){0.f,0.f,0.f,0.f};

    const int c0 = wid >> 1;   // wave's 9 relevant chunks: [c0, c0+9)
    const int pxr = (l15 & 12) << 1;       // V read-side col XOR (row = l15)
    // butterfly step-2 partner: quads 1<->2 exchange (lane ^ 48), 0/3 keep
    const int xl = (quad == 1 || quad == 2) ? (lane ^ 48) : lane;

    for (int i = 0; i < NCHT; ++i) {
        // staging first: SWRITE(i+1)'s vmcnt wait covers a load issued a full
        // iteration ago (was: issued-and-drained inside one iteration, with
        // the vmcnt(0) convoy immediately before __syncthreads).
        if (i + 1 < NCHT) SWRITE(i + 1);   // buf (i+1)%3: last read in iter i-2
        if (i + 2 < NCHT) SLOAD(i + 2);

        if ((unsigned)(i - c0) < 9u) {
            const h16* Kb = Kbuf[i % 3];
            const h16* Vb = Vbuf[i % 3];

            f16x8 bK00 = *(const f16x8*)&Kb[ l15      * KSTR + quad*8];
            f16x8 bK01 = *(const f16x8*)&Kb[ l15      * KSTR + 32 + quad*8];
            f16x8 bK10 = *(const f16x8*)&Kb[(16+l15)  * KSTR + quad*8];
            f16x8 bK11 = *(const f16x8*)&Kb[(16+l15)  * KSTR + 32 + quad*8];

            // swapped QK^T: S^T[key][q].  Lane (l15,quad):
            //   s0[r] = S[q=l15][k = 4*quad + r],  s1[r] = same + 16
            f32x4 s0 = (f32x4){0.f,0.f,0.f,0.f};
            s0 = __builtin_amdgcn_mfma_f32_16x16x32_f16(bK00, aQ0, s0, 0, 0, 0);
            s0 = __builtin_amdgcn_mfma_f32_16x16x32_f16(bK01, aQ1, s0, 0, 0, 0);
            f32x4 s1 = (f32x4){0.f,0.f,0.f,0.f};
            s1 = __builtin_amdgcn_mfma_f32_16x16x32_f16(bK10, aQ0, s1, 0, 0, 0);
            s1 = __builtin_amdgcn_mfma_f32_16x16x32_f16(bK11, aQ1, s1, 0, 0, 0);

            const int colb = kbase + i*32 + quad*4;
            float pl[4], ph[4];
            #pragma unroll
            for (int r = 0; r < 4; ++r) {
                int c_ = colb + r;
                float v0 = ((unsigned)(c_      - lo) <= span) ? s0[r] : -1e30f;
                float v1 = ((unsigned)(c_ + 16 - lo) <= span) ? s1[r] : -1e30f;
                pl[r] = exp2f(v0);    // exp2(-1e30)=0 -> clamped K/V rows vanish
                ph[r] = exp2f(v1);
            }
            l_lane += ((pl[0]+pl[1]) + (pl[2]+pl[3]))
                    + ((ph[0]+ph[1]) + (ph[2]+ph[3]));

            // ---- in-register P transpose -> PV A-operand ----
            // source word (q1,q0,w1,w0) holds k-pair p=(w1,q1,q0,w0); target
            // lane/word (Q1,Q0,W1,W0) wants p=(Q1,Q0,W1,W0).  Two swaps:
            // swap(q0,w1) via xor-16 swizzle, then swap(q1,q0) via lane^48.
            int u0 = __builtin_bit_cast(int, pk(pl[0], pl[1]));  // pair 2q
            int u1 = __builtin_bit_cast(int, pk(pl[2], pl[3]));  // pair 2q+1
            int u2 = __builtin_bit_cast(int, pk(ph[0], ph[1]));  // pair 8+2q
            int u3 = __builtin_bit_cast(int, pk(ph[2], ph[3]));  // pair 8+2q+1
            {
                const bool q0b = (quad & 1);
                int s0w = q0b ? u0 : u2;      // q0=1 sends lo, q0=0 sends hi
                int s1w = q0b ? u1 : u3;
                int r0 = __builtin_amdgcn_ds_swizzle(s0w, 0x401F);  // lane^16
                int r1 = __builtin_amdgcn_ds_swizzle(s1w, 0x401F);
                if (q0b) { u0 = r0; u1 = r1; } else { u2 = r0; u3 = r1; }
            }
            u0 = __shfl(u0, xl);  u1 = __shfl(u1, xl);
            u2 = __shfl(u2, xl);  u3 = __shfl(u3, xl);
            i32x4 uu; uu[0]=u0; uu[1]=u1; uu[2]=u2; uu[3]=u3;
            f16x8 aP = __builtin_bit_cast(f16x8, uu);   // P[l15][8*quad + 0..7]

            #pragma unroll
            for (int t = 0; t < 4; ++t) {
                // invert the V key swizzle: rot by t (h bits 4-5), XOR by l15>>2
                f16x8 bV = *(const f16x8*)&Vb[(t*16 + l15) * VSTR2 +
                                              (((quad*8 + (t << 3)) & 31) ^ pxr)];
                Oacc[t] = __builtin_amdgcn_mfma_f32_16x16x32_f16(aP, bV, Oacc[t], 0, 0, 0);
            }
        }

        __syncthreads();                   // one barrier per chunk (triple buffer)
    }
    #undef SLOAD
    #undef SWRITE

    // ---- epilogue: l lives per-lane (row q=l15); reduce across quads ----
    float l = l_lane;
    l += __shfl_xor(l, 16);
    l += __shfl_xor(l, 32);
    const float inv = 1.0f / l;            // lane (q, any quad) holds row-q inv

    float* op = Og + ((long)(b * S_LEN + q0 + wid*16) * NHEAD + head) * HDIM;
    #pragma unroll
    for (int r = 0; r < 4; ++r) {
        // O-tile row for this lane is quad*4+r; fetch that row's inv from the
        // lane whose l15 == quad*4+r (quad-0 group holds it like all others).
        float invr = __shfl(inv, quad*4 + r);
        #pragma unroll
        for (int t = 0; t < 4; ++t) {
            op[(quad*4 + r) * rowstride + t*16 + l15] = Oacc[t][r] * invr;
        }
    }
}

extern "C" void kernel_launch(void* const* d_in, const int* in_sizes, int n_in,
                              void* d_out, int out_size, void* d_ws, size_t ws_size,
                              hipStream_t stream) {
    const float* q = (const float*)d_in[0];
    const float* k = (const float*)d_in[1];
    const float* v = (const float*)d_in[2];
    float* out = (float*)d_out;
    const int batch = in_sizes[0] / (S_LEN * NHEAD * HDIM);
    dim3 grid(NQT, NHEAD, batch);
    wattn<<<grid, 512, 0, stream>>>(q, k, v, out);
}